// Round 1
// baseline (6371.227 us; speedup 1.0000x reference)
//
#include <hip/hip_runtime.h>
#include <math.h>

#define TPB 256

// ---------------------------------------------------------------------------
// Direct 3x3 conv, pad=1, stride template. Block = 256 threads = 16x16 output
// tile. Each block computes 4 consecutive output channels (co_base+cog*4..+3)
// for one batch image. Input tile staged in LDS per ci; 9 neighbor values
// cached in registers and reused across the 4 output channels (36 FMA : 9
// ds_read per ci per thread). Weights are block-uniform -> scalar loads.
// co_base/Cout_buf allow writing a channel-chunk of the weight's output space
// into a compact buffer (used for chunked offset convs).
// ---------------------------------------------------------------------------
template <int STRIDE>
__global__ __launch_bounds__(256) void conv3x3_k(
    const float* __restrict__ in, const float* __restrict__ wgt,
    const float* __restrict__ bias, float* __restrict__ out,
    int N, int Cin, int H, int W, int Cout_buf, int Ho, int Wo,
    int relu, int co_base)
{
    constexpr int IT = 15 * STRIDE + 3;     // 18 (s=1) or 33 (s=2)
    __shared__ float tile[IT * IT];
    const int tid = threadIdx.x;
    const int tx = tid & 15, ty = tid >> 4;
    const int coutg = Cout_buf >> 2;
    const int n    = blockIdx.z / coutg;
    const int cog  = blockIdx.z - n * coutg;
    const int co0  = cog << 2;              // local channel in out buffer
    const int ox   = (blockIdx.x << 4) + tx;
    const int oy   = (blockIdx.y << 4) + ty;
    const int ix0  = (blockIdx.x << 4) * STRIDE - 1;
    const int iy0  = (blockIdx.y << 4) * STRIDE - 1;
    const float* inN = in + (size_t)n * Cin * H * W;
    float acc[4] = {0.f, 0.f, 0.f, 0.f};

    for (int ci = 0; ci < Cin; ++ci) {
        const float* plane = inN + (size_t)ci * H * W;
        __syncthreads();
        for (int i = tid; i < IT * IT; i += TPB) {
            int r = i / IT, c = i - r * IT;
            int yy = iy0 + r, xx = ix0 + c;
            float v = 0.f;
            if (yy >= 0 && yy < H && xx >= 0 && xx < W) v = plane[yy * W + xx];
            tile[i] = v;
        }
        __syncthreads();
        const int ly = ty * STRIDE, lx = tx * STRIDE;
        float nb[9];
#pragma unroll
        for (int ky = 0; ky < 3; ++ky)
#pragma unroll
            for (int kx = 0; kx < 3; ++kx)
                nb[ky * 3 + kx] = tile[(ly + ky) * IT + lx + kx];
        const float* wp = wgt + ((size_t)(co_base + co0) * Cin + ci) * 9;
#pragma unroll
        for (int j = 0; j < 4; ++j) {
            const float* w9 = wp + (size_t)j * Cin * 9;
            float a = acc[j];
#pragma unroll
            for (int k = 0; k < 9; ++k) a += nb[k] * w9[k];
            acc[j] = a;
        }
    }
#pragma unroll
    for (int j = 0; j < 4; ++j) {
        float v = acc[j];
        if (bias) v += bias[co_base + co0 + j];
        if (relu) v = fmaxf(v, 0.f);
        out[(((size_t)n * Cout_buf + (co0 + j)) * Ho + oy) * Wo + ox] = v;
    }
}

// ---------------------------------------------------------------------------
// BatchNorm (training-mode batch stats, biased var)
// ---------------------------------------------------------------------------
__global__ void zero_k(float* p, int n)
{
    int i = blockIdx.x * TPB + threadIdx.x;
    if (i < n) p[i] = 0.f;
}

__global__ __launch_bounds__(256) void bn_stats_k(
    const float* __restrict__ x, float* __restrict__ stats,
    int C, int HWlog, int NHW, int SPLIT)
{
    const int c = blockIdx.y, sb = blockIdx.x, tid = threadIdx.x;
    const int HWm = (1 << HWlog) - 1;
    float s = 0.f, s2 = 0.f;
    for (int i = sb * TPB + tid; i < NHW; i += SPLIT * TPB) {
        int nn = i >> HWlog, p = i & HWm;
        float v = x[(((size_t)nn * C + c) << HWlog) + p];
        s += v;
        s2 += v * v;
    }
    __shared__ float r1[TPB], r2[TPB];
    r1[tid] = s; r2[tid] = s2;
    __syncthreads();
    for (int d = TPB / 2; d > 0; d >>= 1) {
        if (tid < d) { r1[tid] += r1[tid + d]; r2[tid] += r2[tid + d]; }
        __syncthreads();
    }
    if (tid == 0) {
        atomicAdd(&stats[2 * c], r1[0]);
        atomicAdd(&stats[2 * c + 1], r2[0]);
    }
}

__global__ __launch_bounds__(256) void bn_apply_k(
    float* __restrict__ x, const float* __restrict__ stats,
    const float* __restrict__ g, const float* __restrict__ b,
    int Cm1, int HWlog, float invcnt, int total)
{
    int idx = blockIdx.x * TPB + threadIdx.x;
    if (idx >= total) return;
    int c = (idx >> HWlog) & Cm1;
    float mean = stats[2 * c] * invcnt;
    float var  = fmaxf(stats[2 * c + 1] * invcnt - mean * mean, 0.f);
    float sc   = g[c] / sqrtf(var + 1e-5f);
    x[idx] = (x[idx] - mean) * sc + b[c];
}

// ---------------------------------------------------------------------------
// Deformable bilinear gather. The torch-faithful reshape means for flat
// chunk index idx (over (bi, ci_local, p)): dy = off[2*idx], dx = off[2*idx+1].
// act/out use the FULL (N,C,H,W) layout; off is the compact chunk buffer.
// ---------------------------------------------------------------------------
__global__ __launch_bounds__(256) void deform_k(
    const float* __restrict__ act, const float* __restrict__ off,
    float* __restrict__ out,
    int HWlog, int Wlog, int H, int W, int CClog, int Clog, int c0, int total)
{
    int idx = blockIdx.x * TPB + threadIdx.x;
    if (idx >= total) return;
    int p = idx & ((1 << HWlog) - 1);
    int y = p >> Wlog, x = p & (W - 1);
    int l   = idx >> HWlog;               // bi*CC + ci_local
    int bi  = l >> CClog;
    int cil = l & ((1 << CClog) - 1);
    size_t abase = ((size_t)((bi << Clog) + c0 + cil)) << HWlog;

    float2 o = ((const float2*)off)[idx];
    float cy = fminf(fmaxf((float)y + o.x, 0.f), (float)(H - 1));
    float cx = fminf(fmaxf((float)x + o.y, 0.f), (float)(W - 1));
    float y0f = floorf(cy), x0f = floorf(cx);
    float y1f = ceilf(cy),  x1f = ceilf(cx);
    float tyy = cy - y0f, txx = cx - x0f;
    int y0 = (int)y0f, y1 = (int)y1f, x0 = (int)x0f, x1 = (int)x1f;
    const float* pl = act + abase;
    float vlt = pl[(y0 << Wlog) + x0];
    float vrt = pl[(y1 << Wlog) + x0];
    float vlb = pl[(y0 << Wlog) + x1];
    float vrb = pl[(y1 << Wlog) + x1];
    float vt = tyy * (vrt - vlt) + vlt;
    float vb = tyy * (vrb - vlb) + vlb;
    out[abase + p] = txx * (vb - vt) + vt;
}

// ---------------------------------------------------------------------------
// Global average pool: one wave per (n,c) plane
// ---------------------------------------------------------------------------
__global__ __launch_bounds__(64) void gap_k(
    const float* __restrict__ x, float* __restrict__ pooled, int HW, float inv)
{
    int bc = blockIdx.x;
    float s = 0.f;
    for (int i = threadIdx.x; i < HW; i += 64) s += x[(size_t)bc * HW + i];
#pragma unroll
    for (int d = 32; d > 0; d >>= 1) s += __shfl_down(s, d);
    if (threadIdx.x == 0) pooled[bc] = s * inv;
}

// ---------------------------------------------------------------------------
// FC (128 -> 10) + softmax, one block per batch row
// ---------------------------------------------------------------------------
__global__ __launch_bounds__(64) void fc_softmax_k(
    const float* __restrict__ pooled, const float* __restrict__ fw,
    const float* __restrict__ fb, float* __restrict__ outp)
{
    int n = blockIdx.x;
    __shared__ float logits[10];
    int k = threadIdx.x;
    if (k < 10) {
        float s = fb[k];
        const float* row = pooled + n * 128;
        const float* wr  = fw + k * 128;
        for (int c = 0; c < 128; ++c) s += row[c] * wr[c];
        logits[k] = s;
    }
    __syncthreads();
    if (k < 10) {
        float m = logits[0];
#pragma unroll
        for (int j = 1; j < 10; ++j) m = fmaxf(m, logits[j]);
        float den = 0.f;
#pragma unroll
        for (int j = 0; j < 10; ++j) den += expf(logits[j] - m);
        outp[n * 10 + k] = expf(logits[k] - m) / den;
    }
}

// ---------------------------------------------------------------------------
extern "C" void kernel_launch(void* const* d_in, const int* in_sizes, int n_in,
                              void* d_out, int out_size, void* d_ws, size_t ws_size,
                              hipStream_t stream)
{
    const float* x     = (const float*)d_in[0];
    const float* c11w  = (const float*)d_in[1];
    const float* c11b  = (const float*)d_in[2];
    const float* bn11g = (const float*)d_in[3];
    const float* bn11b = (const float*)d_in[4];
    const float* o12w  = (const float*)d_in[5];
    const float* c12w  = (const float*)d_in[6];
    const float* c12b  = (const float*)d_in[7];
    const float* bn12g = (const float*)d_in[8];
    const float* bn12b = (const float*)d_in[9];
    const float* o21w  = (const float*)d_in[10];
    const float* c21w  = (const float*)d_in[11];
    const float* c21b  = (const float*)d_in[12];
    const float* bn21g = (const float*)d_in[13];
    const float* bn21b = (const float*)d_in[14];
    const float* o22w  = (const float*)d_in[15];
    const float* c22w  = (const float*)d_in[16];
    const float* c22b  = (const float*)d_in[17];
    const float* bn22g = (const float*)d_in[18];
    const float* bn22b = (const float*)d_in[19];
    const float* fcw   = (const float*)d_in[20];
    const float* fcb   = (const float*)d_in[21];
    float* outp = (float*)d_out;

    const int N = 32;
    float* ws     = (float*)d_ws;
    float* ACT0   = ws;                               // 16,777,216 floats (max act)
    float* ACT1   = ws + 16777216;                    // 16,777,216
    float* OFF    = ws + 2 * 16777216;                //  8,388,608 (chunked off buf)
    float* STATS  = ws + 2 * 16777216 + 8388608;      //        256
    float* POOLED = STATS + 256;                      //      4,096

    auto conv = [&](const float* in, const float* w, const float* b, float* out,
                    int Cin, int H, int W, int CoutBuf, int stride, int relu,
                    int co_base) {
        int Ho = (stride == 1) ? H : H / 2;
        int Wo = (stride == 1) ? W : W / 2;
        dim3 g(Wo / 16, Ho / 16, N * (CoutBuf / 4));
        if (stride == 1)
            conv3x3_k<1><<<g, TPB, 0, stream>>>(in, w, b, out, N, Cin, H, W,
                                                CoutBuf, Ho, Wo, relu, co_base);
        else
            conv3x3_k<2><<<g, TPB, 0, stream>>>(in, w, b, out, N, Cin, H, W,
                                                CoutBuf, Ho, Wo, relu, co_base);
    };

    auto bn = [&](float* a, const float* g_, const float* b_, int C, int HWlog) {
        int HW = 1 << HWlog;
        int NHW = N * HW;
        int total = N * C * HW;
        zero_k<<<1, TPB, 0, stream>>>(STATS, 256);
        dim3 gs(32, C);
        bn_stats_k<<<gs, TPB, 0, stream>>>(a, STATS, C, HWlog, NHW, 32);
        bn_apply_k<<<(total + TPB - 1) / TPB, TPB, 0, stream>>>(
            a, STATS, g_, b_, C - 1, HWlog, 1.f / (float)NHW, total);
    };

    // offset conv + bilinear deform, chunked over C/4 channels to bound ws
    auto deform = [&](const float* act, const float* ow, float* outd,
                      int C, int Clog, int H, int W, int HWlog, int Wlog) {
        int CC = C / 4;
        int CClog = Clog - 2;
        for (int ch = 0; ch < 4; ++ch) {
            int c0 = ch * CC;
            conv(act, ow, nullptr, OFF, C, H, W, 2 * CC, 1, 0, 2 * c0);
            int total = N * CC * (1 << HWlog);
            deform_k<<<(total + TPB - 1) / TPB, TPB, 0, stream>>>(
                act, OFF, outd, HWlog, Wlog, H, W, CClog, Clog, c0, total);
        }
    };

    // ---- stage 1: conv11 (1->32, 128x128, s1) + relu + bn ----
    conv(x, c11w, c11b, ACT0, 1, 128, 128, 32, 1, 1, 0);
    bn(ACT0, bn11g, bn11b, 32, 14);
    // ---- deform 12 (C=32 @128x128) ----
    deform(ACT0, o12w, ACT1, 32, 5, 128, 128, 14, 7);
    // ---- conv12 (32->64, s2) + relu + bn ----
    conv(ACT1, c12w, c12b, ACT0, 32, 128, 128, 64, 2, 1, 0);
    bn(ACT0, bn12g, bn12b, 64, 12);
    // ---- deform 21 (C=64 @64x64) ----
    deform(ACT0, o21w, ACT1, 64, 6, 64, 64, 12, 6);
    // ---- conv21 (64->128, s1) + relu + bn ----
    conv(ACT1, c21w, c21b, ACT0, 64, 64, 64, 128, 1, 1, 0);
    bn(ACT0, bn21g, bn21b, 128, 12);
    // ---- deform 22 (C=128 @64x64) ----
    deform(ACT0, o22w, ACT1, 128, 7, 64, 64, 12, 6);
    // ---- conv22 (128->128, s2) + relu + bn ----
    conv(ACT1, c22w, c22b, ACT0, 128, 64, 64, 128, 2, 1, 0);
    bn(ACT0, bn22g, bn22b, 128, 10);
    // ---- GAP + FC + softmax ----
    gap_k<<<N * 128, 64, 0, stream>>>(ACT0, POOLED, 1024, 1.f / 1024.f);
    fc_softmax_k<<<N, 64, 0, stream>>>(POOLED, fcw, fcb, outp);
}

// Round 2
// 2521.839 us; speedup vs baseline: 2.5264x; 2.5264x over previous
//
#include <hip/hip_runtime.h>
#include <math.h>

#define TPB 256
typedef unsigned short u16;
typedef short v8s __attribute__((ext_vector_type(8)));
typedef float v4f __attribute__((ext_vector_type(4)));

// ---------------------------------------------------------------------------
// fp32 -> bf16 (RNE) helpers
// ---------------------------------------------------------------------------
__device__ __forceinline__ u16 f2bf(float v) {
    unsigned int u = __builtin_bit_cast(unsigned int, v);
    return (u16)((u + 0x7fffu + ((u >> 16) & 1u)) >> 16);
}

__global__ __launch_bounds__(256) void cast_k(const float* __restrict__ src,
                                              u16* __restrict__ dst, int n) {
    int i = blockIdx.x * TPB + threadIdx.x;
    if (i < n) dst[i] = f2bf(src[i]);
}

// ---------------------------------------------------------------------------
// im2col: act fp32 [Ng][Cin][H][W] -> B bf16 [Ng][HWo][K], K=Cin*9,
// k = ci*9 + ky*3 + kx  (matches flat OIHW weight layout -> weight cast is flat)
// ---------------------------------------------------------------------------
__global__ __launch_bounds__(256) void im2col_k(
    const float* __restrict__ act, u16* __restrict__ Bb,
    int Cin, int H, int W, int Wo, int Wolog, int stride, int K, int HWo)
{
    const int t = threadIdx.x;
    const int kk = t & 31, pp = t >> 5;
    const int k = blockIdx.x * 32 + kk;
    const int p = blockIdx.y * 8 + pp;
    const int g = blockIdx.z;
    const int ci = k / 9, kpos = k - ci * 9;
    const int ky = kpos / 3, kx = kpos - ky * 3;
    const int oy = p >> Wolog, ox = p & (Wo - 1);
    const int iy = oy * stride + ky - 1, ix = ox * stride + kx - 1;
    float v = 0.f;
    if (iy >= 0 && iy < H && ix >= 0 && ix < W)
        v = act[((size_t)(g * Cin + ci) * H + iy) * W + ix];
    Bb[((size_t)g * HWo + p) * K + k] = f2bf(v);
}

// ---------------------------------------------------------------------------
// MFMA GEMM: C[g][m][pix] = sum_k A[m][k] * B[g][pix][k]  (+bias, relu)
// A bf16 [M][K], B bf16 [Ng][Npix][K], C fp32. Block = 256 thr = 4 waves,
// wave tile 64x64 (4x4 MFMA 16x16x32), block tile (WGM*64) x (WGN*64).
// LDS rows padded to 40 bf16 (stride 20 dwords -> 2-way bank aliasing = free).
// Register-prefetch double buffering of global loads across the k-step.
// ---------------------------------------------------------------------------
template <int WGM, int WGN>
__global__ __launch_bounds__(256) void gemm_conv_k(
    const u16* __restrict__ A, const u16* __restrict__ B, float* __restrict__ C,
    const float* __restrict__ bias, int M, int K, int Npix, int relu)
{
    constexpr int BM = WGM * 64, BN = WGN * 64;
    constexpr int AC = WGM, BC = WGN;       // 16B chunks per thread per tile
    __shared__ u16 As[BM * 40];
    __shared__ u16 Bs[BN * 40];
    const int t = threadIdx.x;
    const int g = blockIdx.z;
    const int p0 = blockIdx.x * BN;
    const int m0 = blockIdx.y * BM;
    const u16* Bimg = B + (size_t)g * Npix * K;

    uint4 ar[AC], br[BC];
    auto loadA = [&](int k0) {
#pragma unroll
        for (int i = 0; i < AC; ++i) {
            int ch = t + i * 256, m = ch >> 2, c = ch & 3;
            ar[i] = *(const uint4*)(A + (size_t)(m0 + m) * K + k0 + c * 8);
        }
    };
    auto loadB = [&](int k0) {
#pragma unroll
        for (int i = 0; i < BC; ++i) {
            int ch = t + i * 256, nr = ch >> 2, c = ch & 3;
            br[i] = *(const uint4*)(Bimg + (size_t)(p0 + nr) * K + k0 + c * 8);
        }
    };

    v4f acc[4][4];
#pragma unroll
    for (int mi = 0; mi < 4; ++mi)
#pragma unroll
        for (int ni = 0; ni < 4; ++ni) acc[mi][ni] = (v4f){0.f, 0.f, 0.f, 0.f};

    const int lane = t & 63, wave = t >> 6;
    const int wm = wave % WGM, wn = wave / WGM;
    const int la = lane & 15, quad = lane >> 4;

    loadA(0); loadB(0);
    const int nk = K >> 5;
    for (int kk = 0; kk < nk; ++kk) {
        __syncthreads();
#pragma unroll
        for (int i = 0; i < AC; ++i) {
            int ch = t + i * 256;
            *(uint4*)(&As[(ch >> 2) * 40 + (ch & 3) * 8]) = ar[i];
        }
#pragma unroll
        for (int i = 0; i < BC; ++i) {
            int ch = t + i * 256;
            *(uint4*)(&Bs[(ch >> 2) * 40 + (ch & 3) * 8]) = br[i];
        }
        __syncthreads();
        if (kk + 1 < nk) { loadA((kk + 1) << 5); loadB((kk + 1) << 5); }
        v8s a[4], b[4];
#pragma unroll
        for (int mi = 0; mi < 4; ++mi)
            a[mi] = *(const v8s*)(&As[(wm * 64 + mi * 16 + la) * 40 + quad * 8]);
#pragma unroll
        for (int ni = 0; ni < 4; ++ni)
            b[ni] = *(const v8s*)(&Bs[(wn * 64 + ni * 16 + la) * 40 + quad * 8]);
#pragma unroll
        for (int mi = 0; mi < 4; ++mi)
#pragma unroll
            for (int ni = 0; ni < 4; ++ni)
                acc[mi][ni] = __builtin_amdgcn_mfma_f32_16x16x32_bf16(
                    a[mi], b[ni], acc[mi][ni], 0, 0, 0);
    }

    float* Cimg = C + (size_t)g * M * Npix;
#pragma unroll
    for (int mi = 0; mi < 4; ++mi) {
#pragma unroll
        for (int r = 0; r < 4; ++r) {
            int row = m0 + wm * 64 + mi * 16 + quad * 4 + r;
            float bv = bias ? bias[row] : 0.f;
#pragma unroll
            for (int ni = 0; ni < 4; ++ni) {
                int col = p0 + wn * 64 + ni * 16 + la;
                float v = acc[mi][ni][r] + bv;
                if (relu) v = fmaxf(v, 0.f);
                Cimg[(size_t)row * Npix + col] = v;
            }
        }
    }
}

// ---------------------------------------------------------------------------
// Direct 3x3 conv (kept for conv11, Cin=1 only)
// ---------------------------------------------------------------------------
template <int STRIDE>
__global__ __launch_bounds__(256) void conv3x3_k(
    const float* __restrict__ in, const float* __restrict__ wgt,
    const float* __restrict__ bias, float* __restrict__ out,
    int N, int Cin, int H, int W, int Cout_buf, int Ho, int Wo,
    int relu, int co_base)
{
    constexpr int IT = 15 * STRIDE + 3;
    __shared__ float tile[IT * IT];
    const int tid = threadIdx.x;
    const int tx = tid & 15, ty = tid >> 4;
    const int coutg = Cout_buf >> 2;
    const int n = blockIdx.z / coutg;
    const int cog = blockIdx.z - n * coutg;
    const int co0 = cog << 2;
    const int ox = (blockIdx.x << 4) + tx;
    const int oy = (blockIdx.y << 4) + ty;
    const int ix0 = (blockIdx.x << 4) * STRIDE - 1;
    const int iy0 = (blockIdx.y << 4) * STRIDE - 1;
    const float* inN = in + (size_t)n * Cin * H * W;
    float acc[4] = {0.f, 0.f, 0.f, 0.f};

    for (int ci = 0; ci < Cin; ++ci) {
        const float* plane = inN + (size_t)ci * H * W;
        __syncthreads();
        for (int i = tid; i < IT * IT; i += TPB) {
            int r = i / IT, c = i - r * IT;
            int yy = iy0 + r, xx = ix0 + c;
            float v = 0.f;
            if (yy >= 0 && yy < H && xx >= 0 && xx < W) v = plane[yy * W + xx];
            tile[i] = v;
        }
        __syncthreads();
        const int ly = ty * STRIDE, lx = tx * STRIDE;
        float nb[9];
#pragma unroll
        for (int ky = 0; ky < 3; ++ky)
#pragma unroll
            for (int kx = 0; kx < 3; ++kx)
                nb[ky * 3 + kx] = tile[(ly + ky) * IT + lx + kx];
        const float* wp = wgt + ((size_t)(co_base + co0) * Cin + ci) * 9;
#pragma unroll
        for (int j = 0; j < 4; ++j) {
            const float* w9 = wp + (size_t)j * Cin * 9;
            float a = acc[j];
#pragma unroll
            for (int k = 0; k < 9; ++k) a += nb[k] * w9[k];
            acc[j] = a;
        }
    }
#pragma unroll
    for (int j = 0; j < 4; ++j) {
        float v = acc[j];
        if (bias) v += bias[co_base + co0 + j];
        if (relu) v = fmaxf(v, 0.f);
        out[(((size_t)n * Cout_buf + (co0 + j)) * Ho + oy) * Wo + ox] = v;
    }
}

// ---------------------------------------------------------------------------
// BatchNorm (training-mode batch stats, biased var)
// ---------------------------------------------------------------------------
__global__ void zero_k(float* p, int n)
{
    int i = blockIdx.x * TPB + threadIdx.x;
    if (i < n) p[i] = 0.f;
}

__global__ __launch_bounds__(256) void bn_stats_k(
    const float* __restrict__ x, float* __restrict__ stats,
    int C, int HWlog, int NHW, int SPLIT)
{
    const int c = blockIdx.y, sb = blockIdx.x, tid = threadIdx.x;
    const int HWm = (1 << HWlog) - 1;
    float s = 0.f, s2 = 0.f;
    for (int i = sb * TPB + tid; i < NHW; i += SPLIT * TPB) {
        int nn = i >> HWlog, p = i & HWm;
        float v = x[(((size_t)nn * C + c) << HWlog) + p];
        s += v;
        s2 += v * v;
    }
    __shared__ float r1[TPB], r2[TPB];
    r1[tid] = s; r2[tid] = s2;
    __syncthreads();
    for (int d = TPB / 2; d > 0; d >>= 1) {
        if (tid < d) { r1[tid] += r1[tid + d]; r2[tid] += r2[tid + d]; }
        __syncthreads();
    }
    if (tid == 0) {
        atomicAdd(&stats[2 * c], r1[0]);
        atomicAdd(&stats[2 * c + 1], r2[0]);
    }
}

__global__ __launch_bounds__(256) void bn_apply_k(
    float* __restrict__ x, const float* __restrict__ stats,
    const float* __restrict__ g, const float* __restrict__ b,
    int Cm1, int HWlog, float invcnt, int total)
{
    int idx = blockIdx.x * TPB + threadIdx.x;
    if (idx >= total) return;
    int c = (idx >> HWlog) & Cm1;
    float mean = stats[2 * c] * invcnt;
    float var  = fmaxf(stats[2 * c + 1] * invcnt - mean * mean, 0.f);
    float sc   = g[c] / sqrtf(var + 1e-5f);
    x[idx] = (x[idx] - mean) * sc + b[c];
}

// ---------------------------------------------------------------------------
// Deformable bilinear gather. For flat index idx over (bi, c, p):
// dy = offflat[2*idx], dx = offflat[2*idx+1] (torch-faithful reshape).
// ---------------------------------------------------------------------------
__global__ __launch_bounds__(256) void deform_k(
    const float* __restrict__ act, const float* __restrict__ off,
    float* __restrict__ out,
    int HWlog, int Wlog, int H, int W, int CClog, int Clog, int c0, int total)
{
    int idx = blockIdx.x * TPB + threadIdx.x;
    if (idx >= total) return;
    int p = idx & ((1 << HWlog) - 1);
    int y = p >> Wlog, x = p & (W - 1);
    int l   = idx >> HWlog;
    int bi  = l >> CClog;
    int cil = l & ((1 << CClog) - 1);
    size_t abase = ((size_t)((bi << Clog) + c0 + cil)) << HWlog;

    float2 o = ((const float2*)off)[idx];
    float cy = fminf(fmaxf((float)y + o.x, 0.f), (float)(H - 1));
    float cx = fminf(fmaxf((float)x + o.y, 0.f), (float)(W - 1));
    float y0f = floorf(cy), x0f = floorf(cx);
    float tyy = cy - y0f, txx = cx - x0f;
    int y0 = (int)y0f, y1 = (int)ceilf(cy), x0 = (int)x0f, x1 = (int)ceilf(cx);
    const float* pl = act + abase;
    float vlt = pl[(y0 << Wlog) + x0];
    float vrt = pl[(y1 << Wlog) + x0];
    float vlb = pl[(y0 << Wlog) + x1];
    float vrb = pl[(y1 << Wlog) + x1];
    float vt = tyy * (vrt - vlt) + vlt;
    float vb = tyy * (vrb - vlb) + vlb;
    out[abase + p] = txx * (vb - vt) + vt;
}

// ---------------------------------------------------------------------------
__global__ __launch_bounds__(64) void gap_k(
    const float* __restrict__ x, float* __restrict__ pooled, int HW, float inv)
{
    int bc = blockIdx.x;
    float s = 0.f;
    for (int i = threadIdx.x; i < HW; i += 64) s += x[(size_t)bc * HW + i];
#pragma unroll
    for (int d = 32; d > 0; d >>= 1) s += __shfl_down(s, d);
    if (threadIdx.x == 0) pooled[bc] = s * inv;
}

__global__ __launch_bounds__(64) void fc_softmax_k(
    const float* __restrict__ pooled, const float* __restrict__ fw,
    const float* __restrict__ fb, float* __restrict__ outp)
{
    int n = blockIdx.x;
    __shared__ float logits[10];
    int k = threadIdx.x;
    if (k < 10) {
        float s = fb[k];
        const float* row = pooled + n * 128;
        const float* wr  = fw + k * 128;
        for (int c = 0; c < 128; ++c) s += row[c] * wr[c];
        logits[k] = s;
    }
    __syncthreads();
    if (k < 10) {
        float m = logits[0];
#pragma unroll
        for (int j = 1; j < 10; ++j) m = fmaxf(m, logits[j]);
        float den = 0.f;
#pragma unroll
        for (int j = 0; j < 10; ++j) den += expf(logits[j] - m);
        outp[n * 10 + k] = expf(logits[k] - m) / den;
    }
}

// ---------------------------------------------------------------------------
extern "C" void kernel_launch(void* const* d_in, const int* in_sizes, int n_in,
                              void* d_out, int out_size, void* d_ws, size_t ws_size,
                              hipStream_t stream)
{
    const float* x     = (const float*)d_in[0];
    const float* c11w  = (const float*)d_in[1];
    const float* c11b  = (const float*)d_in[2];
    const float* bn11g = (const float*)d_in[3];
    const float* bn11b = (const float*)d_in[4];
    const float* o12w  = (const float*)d_in[5];
    const float* c12w  = (const float*)d_in[6];
    const float* c12b  = (const float*)d_in[7];
    const float* bn12g = (const float*)d_in[8];
    const float* bn12b = (const float*)d_in[9];
    const float* o21w  = (const float*)d_in[10];
    const float* c21w  = (const float*)d_in[11];
    const float* c21b  = (const float*)d_in[12];
    const float* bn21g = (const float*)d_in[13];
    const float* bn21b = (const float*)d_in[14];
    const float* o22w  = (const float*)d_in[15];
    const float* c22w  = (const float*)d_in[16];
    const float* c22b  = (const float*)d_in[17];
    const float* bn22g = (const float*)d_in[18];
    const float* bn22b = (const float*)d_in[19];
    const float* fcw   = (const float*)d_in[20];
    const float* fcb   = (const float*)d_in[21];
    float* outp = (float*)d_out;

    const int N = 32;
    float* ws     = (float*)d_ws;
    float* ACT0   = ws;                       // 16,777,216 floats
    float* ACT1   = ws + 16777216;            // 16,777,216
    float* STATS  = ws + 33554432;            // 256
    float* POOLED = ws + 33554688;            // 4096
    u16*   WBF    = (u16*)(ws + 33558784);    // 626,688 ushorts
    // group-size-dependent buffers
    size_t fixed_floats = 33872192;           // padded past WBF
    int Ng = 1;
    {
        const int cands[6] = {32, 16, 8, 4, 2, 1};
        for (int i = 0; i < 6; ++i) {
            size_t need = fixed_floats * 4 + (size_t)cands[i] * 13631488u;
            if (need <= ws_size) { Ng = cands[i]; break; }
        }
    }
    float* OFF = ws + fixed_floats;                        // Ng*1,048,576 floats
    u16*   BB  = (u16*)(ws + fixed_floats + (size_t)Ng * 1048576);

    // bf16 weight offsets (ushort index into WBF); flat cast works because
    // k = ci*9 + ky*3 + kx matches OIHW flattening
    u16* wo12 = WBF + 0;        // 64*288
    u16* wc12 = WBF + 18432;    // 64*288
    u16* wo21 = WBF + 36864;    // 128*576
    u16* wc21 = WBF + 110592;   // 128*576
    u16* wo22 = WBF + 184320;   // 256*1152
    u16* wc22 = WBF + 479232;   // 128*1152
    auto cast = [&](const float* s, u16* d, int n) {
        cast_k<<<(n + TPB - 1) / TPB, TPB, 0, stream>>>(s, d, n);
    };
    cast(o12w, wo12, 18432);
    cast(c12w, wc12, 18432);
    cast(o21w, wo21, 73728);
    cast(c21w, wc21, 73728);
    cast(o22w, wo22, 294912);
    cast(c22w, wc22, 147456);

    auto im2col = [&](const float* act, int Cin, int H, int W, int stride) {
        int Wo = W / stride, Ho = H / stride;
        int HWo = Ho * Wo, K = Cin * 9;
        int Wolog = (Wo == 128) ? 7 : (Wo == 64) ? 6 : 5;
        dim3 g(K / 32, HWo / 8, Ng);
        im2col_k<<<g, TPB, 0, stream>>>(act, BB, Cin, H, W, Wo, Wolog, stride, K, HWo);
    };
    auto gemm = [&](const u16* A, float* C, const float* bias,
                    int M, int K, int Npix, int relu) {
        if (M == 64) {
            dim3 g(Npix / 256, 1, Ng);
            gemm_conv_k<1, 4><<<g, TPB, 0, stream>>>(A, BB, C, bias, M, K, Npix, relu);
        } else {
            dim3 g(Npix / 128, M / 128, Ng);
            gemm_conv_k<2, 2><<<g, TPB, 0, stream>>>(A, BB, C, bias, M, K, Npix, relu);
        }
    };
    auto bn = [&](float* a, const float* g_, const float* b_, int C, int HWlog) {
        int HW = 1 << HWlog;
        int NHW = N * HW;
        int total = N * C * HW;
        zero_k<<<1, TPB, 0, stream>>>(STATS, 256);
        dim3 gs(32, C);
        bn_stats_k<<<gs, TPB, 0, stream>>>(a, STATS, C, HWlog, NHW, 32);
        bn_apply_k<<<(total + TPB - 1) / TPB, TPB, 0, stream>>>(
            a, STATS, g_, b_, C - 1, HWlog, 1.f / (float)NHW, total);
    };

    // ---- stage 1: conv11 (1->32, 128x128, s1) direct + relu + bn ----
    {
        dim3 g(8, 8, N * 8);
        conv3x3_k<1><<<g, TPB, 0, stream>>>(x, c11w, c11b, ACT0, N, 1, 128, 128,
                                            32, 128, 128, 1, 0);
    }
    bn(ACT0, bn11g, bn11b, 32, 14);

    // ---- deform12: ACT0 (32ch @128) -> ACT1 ----
    for (int g0 = 0; g0 < N; g0 += Ng) {
        const float* src = ACT0 + (size_t)g0 * 32 * 16384;
        im2col(src, 32, 128, 128, 1);
        gemm(wo12, OFF, nullptr, 64, 288, 16384, 0);
        int total = Ng * 32 * 16384;
        deform_k<<<(total + TPB - 1) / TPB, TPB, 0, stream>>>(
            src, OFF, ACT1 + (size_t)g0 * 32 * 16384, 14, 7, 128, 128, 5, 5, 0, total);
    }
    // ---- conv12 (32->64, s2) + relu + bn ----
    for (int g0 = 0; g0 < N; g0 += Ng) {
        im2col(ACT1 + (size_t)g0 * 32 * 16384, 32, 128, 128, 2);
        gemm(wc12, ACT0 + (size_t)g0 * 64 * 4096, c12b, 64, 288, 4096, 1);
    }
    bn(ACT0, bn12g, bn12b, 64, 12);

    // ---- deform21: ACT0 (64ch @64) -> ACT1 ----
    for (int g0 = 0; g0 < N; g0 += Ng) {
        const float* src = ACT0 + (size_t)g0 * 64 * 4096;
        im2col(src, 64, 64, 64, 1);
        gemm(wo21, OFF, nullptr, 128, 576, 4096, 0);
        int total = Ng * 64 * 4096;
        deform_k<<<(total + TPB - 1) / TPB, TPB, 0, stream>>>(
            src, OFF, ACT1 + (size_t)g0 * 64 * 4096, 12, 6, 64, 64, 6, 6, 0, total);
    }
    // ---- conv21 (64->128, s1) + relu + bn ----
    for (int g0 = 0; g0 < N; g0 += Ng) {
        im2col(ACT1 + (size_t)g0 * 64 * 4096, 64, 64, 64, 1);
        gemm(wc21, ACT0 + (size_t)g0 * 128 * 4096, c21b, 128, 576, 4096, 1);
    }
    bn(ACT0, bn21g, bn21b, 128, 12);

    // ---- deform22: ACT0 (128ch @64) -> ACT1 ----
    for (int g0 = 0; g0 < N; g0 += Ng) {
        const float* src = ACT0 + (size_t)g0 * 128 * 4096;
        im2col(src, 128, 64, 64, 1);
        gemm(wo22, OFF, nullptr, 256, 1152, 4096, 0);
        int total = Ng * 128 * 4096;
        deform_k<<<(total + TPB - 1) / TPB, TPB, 0, stream>>>(
            src, OFF, ACT1 + (size_t)g0 * 128 * 4096, 12, 6, 64, 64, 7, 7, 0, total);
    }
    // ---- conv22 (128->128, s2) + relu + bn ----
    for (int g0 = 0; g0 < N; g0 += Ng) {
        im2col(ACT1 + (size_t)g0 * 128 * 4096, 128, 64, 64, 2);
        gemm(wc22, ACT0 + (size_t)g0 * 128 * 1024, c22b, 128, 1152, 1024, 1);
    }
    bn(ACT0, bn22g, bn22b, 128, 10);

    // ---- GAP + FC + softmax ----
    gap_k<<<N * 128, 64, 0, stream>>>(ACT0, POOLED, 1024, 1.f / 1024.f);
    fc_softmax_k<<<N, 64, 0, stream>>>(POOLED, fcw, fcb, outp);
}

// Round 4
// 907.682 us; speedup vs baseline: 7.0192x; 2.7783x over previous
//
#include <hip/hip_runtime.h>
#include <math.h>

#define TPB 256
typedef unsigned short u16;
typedef short v8s __attribute__((ext_vector_type(8)));
typedef float v4f __attribute__((ext_vector_type(4)));

__device__ __forceinline__ u16 f2bf(float v) {
    unsigned int u = __builtin_bit_cast(unsigned int, v);
    return (u16)((u + 0x7fffu + ((u >> 16) & 1u)) >> 16);
}
__device__ __forceinline__ float bf2f(u16 v) {
    return __builtin_bit_cast(float, (unsigned int)v << 16);
}

// ---------------------------------------------------------------------------
// weight cast + permute: OIHW fp32 -> [co][ky*3+kx][ci] bf16
// ---------------------------------------------------------------------------
__global__ __launch_bounds__(256) void cast_perm_k(
    const float* __restrict__ src, u16* __restrict__ dst, int Cout, int Cin)
{
    int i = blockIdx.x * TPB + threadIdx.x;
    int total = Cout * Cin * 9;
    if (i >= total) return;
    int ci = i % Cin, rest = i / Cin;
    int w = rest % 9, co = rest / 9;
    dst[i] = f2bf(src[(co * Cin + ci) * 9 + w]);
}

// ---------------------------------------------------------------------------
// Implicit-GEMM conv: C[g][m][pix] = sum_k A[m][k]*B[g][pix][k], k=(ky,kx,ci),
// B generated on the fly from NHWC bf16 act. Block=256thr=4 waves, wave tile
// 64x64 (4x4 mfma 16x16x32), block (WGM*64)x(WGN*64). BK=32 k-chunk = one
// (ky,kx) window x 32 contiguous ci -> row load is one contiguous 64B run,
// L1-resident across the 9 windows. LDS rows padded to 40 u16.
// ---------------------------------------------------------------------------
template <int WGM, int WGN>
__global__ __launch_bounds__(256) void gemm_impl_k(
    const u16* __restrict__ A, const u16* __restrict__ act, float* __restrict__ C,
    const float* __restrict__ bias, int M, int K, int Npix, int relu,
    int Cin, int CPWlog, int H, int W, int Wolog, int stride)
{
    constexpr int BM = WGM * 64, BN = WGN * 64, AC = WGM, BC = WGN;
    __shared__ u16 As[BM * 40];
    __shared__ u16 Bs[BN * 40];
    const int t = threadIdx.x;
    const int g = blockIdx.z;
    const int p0 = blockIdx.x * BN;
    const int m0 = blockIdx.y * BM;
    const u16* actg = act + (size_t)g * ((size_t)H * W * Cin);
    const int Wo = 1 << Wolog;
    const int cc8 = (t & 3) * 8;

    int by[BC], bx[BC], rbase[BC];
#pragma unroll
    for (int i = 0; i < BC; ++i) {
        int nr = (t + i * 256) >> 2;
        int p = p0 + nr;
        int oy = p >> Wolog, ox = p & (Wo - 1);
        by[i] = oy * stride - 1;
        bx[i] = ox * stride - 1;
        rbase[i] = (by[i] * W + bx[i]) * Cin + cc8;
    }

    uint4 ar[AC], br[BC];
    auto loadA = [&](int k0) {
#pragma unroll
        for (int i = 0; i < AC; ++i) {
            int m = (t + i * 256) >> 2;
            ar[i] = *(const uint4*)(A + (size_t)(m0 + m) * K + k0 + cc8);
        }
    };
    auto loadB = [&](int kk) {
        int w = kk >> CPWlog;
        int ci0 = (kk - (w << CPWlog)) << 5;
        int ky = w / 3, kx = w - 3 * ky;
        int koff = (ky * W + kx) * Cin + ci0;
#pragma unroll
        for (int i = 0; i < BC; ++i) {
            int iy = by[i] + ky, ix = bx[i] + kx;
            bool ok = ((unsigned)iy < (unsigned)H) && ((unsigned)ix < (unsigned)W);
            uint4 val = {0u, 0u, 0u, 0u};
            if (ok) val = *(const uint4*)(actg + rbase[i] + koff);
            br[i] = val;
        }
    };

    v4f acc[4][4];
#pragma unroll
    for (int mi = 0; mi < 4; ++mi)
#pragma unroll
        for (int ni = 0; ni < 4; ++ni) acc[mi][ni] = (v4f){0.f, 0.f, 0.f, 0.f};

    const int lane = t & 63, wave = t >> 6;
    const int wm = wave % WGM, wn = wave / WGM;
    const int la = lane & 15, quad = lane >> 4;

    loadA(0);
    loadB(0);
    const int nk = K >> 5;
    for (int kk = 0; kk < nk; ++kk) {
        __syncthreads();
#pragma unroll
        for (int i = 0; i < AC; ++i) {
            int ch = t + i * 256;
            *(uint4*)(&As[(ch >> 2) * 40 + (ch & 3) * 8]) = ar[i];
        }
#pragma unroll
        for (int i = 0; i < BC; ++i) {
            int ch = t + i * 256;
            *(uint4*)(&Bs[(ch >> 2) * 40 + (ch & 3) * 8]) = br[i];
        }
        __syncthreads();
        if (kk + 1 < nk) { loadA((kk + 1) << 5); loadB(kk + 1); }
        v8s a[4], b[4];
#pragma unroll
        for (int mi = 0; mi < 4; ++mi)
            a[mi] = *(const v8s*)(&As[(wm * 64 + mi * 16 + la) * 40 + quad * 8]);
#pragma unroll
        for (int ni = 0; ni < 4; ++ni)
            b[ni] = *(const v8s*)(&Bs[(wn * 64 + ni * 16 + la) * 40 + quad * 8]);
#pragma unroll
        for (int mi = 0; mi < 4; ++mi)
#pragma unroll
            for (int ni = 0; ni < 4; ++ni)
                acc[mi][ni] = __builtin_amdgcn_mfma_f32_16x16x32_bf16(
                    a[mi], b[ni], acc[mi][ni], 0, 0, 0);
    }

    float* Cimg = C + (size_t)g * M * Npix;
#pragma unroll
    for (int mi = 0; mi < 4; ++mi) {
#pragma unroll
        for (int r = 0; r < 4; ++r) {
            int row = m0 + wm * 64 + mi * 16 + quad * 4 + r;
            float bv = bias ? bias[row] : 0.f;
#pragma unroll
            for (int ni = 0; ni < 4; ++ni) {
                int col = p0 + wn * 64 + ni * 16 + la;
                float v = acc[mi][ni][r] + bv;
                if (relu) v = fmaxf(v, 0.f);
                Cimg[(size_t)row * Npix + col] = v;
            }
        }
    }
}

// ---------------------------------------------------------------------------
// Direct 3x3 conv (conv11 only, Cin=1), fp32 NCHW out
// ---------------------------------------------------------------------------
template <int STRIDE>
__global__ __launch_bounds__(256) void conv3x3_k(
    const float* __restrict__ in, const float* __restrict__ wgt,
    const float* __restrict__ bias, float* __restrict__ out,
    int N, int Cin, int H, int W, int Cout_buf, int Ho, int Wo,
    int relu, int co_base)
{
    constexpr int IT = 15 * STRIDE + 3;
    __shared__ float tile[IT * IT];
    const int tid = threadIdx.x;
    const int tx = tid & 15, ty = tid >> 4;
    const int coutg = Cout_buf >> 2;
    const int n = blockIdx.z / coutg;
    const int cog = blockIdx.z - n * coutg;
    const int co0 = cog << 2;
    const int ox = (blockIdx.x << 4) + tx;
    const int oy = (blockIdx.y << 4) + ty;
    const int ix0 = (blockIdx.x << 4) * STRIDE - 1;
    const int iy0 = (blockIdx.y << 4) * STRIDE - 1;
    const float* inN = in + (size_t)n * Cin * H * W;
    float acc[4] = {0.f, 0.f, 0.f, 0.f};

    for (int ci = 0; ci < Cin; ++ci) {
        const float* plane = inN + (size_t)ci * H * W;
        __syncthreads();
        for (int i = tid; i < IT * IT; i += TPB) {
            int r = i / IT, c = i - r * IT;
            int yy = iy0 + r, xx = ix0 + c;
            float v = 0.f;
            if (yy >= 0 && yy < H && xx >= 0 && xx < W) v = plane[yy * W + xx];
            tile[i] = v;
        }
        __syncthreads();
        const int ly = ty * STRIDE, lx = tx * STRIDE;
        float nb[9];
#pragma unroll
        for (int ky = 0; ky < 3; ++ky)
#pragma unroll
            for (int kx = 0; kx < 3; ++kx)
                nb[ky * 3 + kx] = tile[(ly + ky) * IT + lx + kx];
        const float* wp = wgt + ((size_t)(co_base + co0) * Cin + ci) * 9;
#pragma unroll
        for (int j = 0; j < 4; ++j) {
            const float* w9 = wp + (size_t)j * Cin * 9;
            float a = acc[j];
#pragma unroll
            for (int k = 0; k < 9; ++k) a += nb[k] * w9[k];
            acc[j] = a;
        }
    }
#pragma unroll
    for (int j = 0; j < 4; ++j) {
        float v = acc[j];
        if (bias) v += bias[co_base + co0 + j];
        if (relu) v = fmaxf(v, 0.f);
        out[(((size_t)n * Cout_buf + (co0 + j)) * Ho + oy) * Wo + ox] = v;
    }
}

// ---------------------------------------------------------------------------
// BatchNorm
// ---------------------------------------------------------------------------
__global__ void zero_k(float* p, int n)
{
    int i = blockIdx.x * TPB + threadIdx.x;
    if (i < n) p[i] = 0.f;
}

__global__ __launch_bounds__(256) void bn_stats_k(
    const float* __restrict__ x, float* __restrict__ stats,
    int C, int HWlog, int NHW, int SPLIT)
{
    const int c = blockIdx.y, sb = blockIdx.x, tid = threadIdx.x;
    const int HWm = (1 << HWlog) - 1;
    float s = 0.f, s2 = 0.f;
    for (int i = sb * TPB + tid; i < NHW; i += SPLIT * TPB) {
        int nn = i >> HWlog, p = i & HWm;
        float v = x[(((size_t)nn * C + c) << HWlog) + p];
        s += v;
        s2 += v * v;
    }
    __shared__ float r1[TPB], r2[TPB];
    r1[tid] = s; r2[tid] = s2;
    __syncthreads();
    for (int d = TPB / 2; d > 0; d >>= 1) {
        if (tid < d) { r1[tid] += r1[tid + d]; r2[tid] += r2[tid + d]; }
        __syncthreads();
    }
    if (tid == 0) {
        atomicAdd(&stats[2 * c], r1[0]);
        atomicAdd(&stats[2 * c + 1], r2[0]);
    }
}

// in-place fp32 NCHW apply (last BN only)
__global__ __launch_bounds__(256) void bn_apply_k(
    float* __restrict__ x, const float* __restrict__ stats,
    const float* __restrict__ g, const float* __restrict__ b,
    int Cm1, int HWlog, float invcnt, int total)
{
    int idx = blockIdx.x * TPB + threadIdx.x;
    if (idx >= total) return;
    int c = (idx >> HWlog) & Cm1;
    float mean = stats[2 * c] * invcnt;
    float var  = fmaxf(stats[2 * c + 1] * invcnt - mean * mean, 0.f);
    float sc   = g[c] / sqrtf(var + 1e-5f);
    x[idx] = (x[idx] - mean) * sc + b[c];
}

// fused BN-apply + NCHW->NHWC transpose + bf16 cast.
// grid (HW/64, C/32, N); block 256; LDS 32x64 tile (pad 65)
__global__ __launch_bounds__(256) void bn_apply_t_k(
    const float* __restrict__ x, const float* __restrict__ stats,
    const float* __restrict__ gamma, const float* __restrict__ beta,
    u16* __restrict__ out, int C, int HWlog, float invcnt)
{
    __shared__ float tile[32 * 65];
    __shared__ float smean[32], ssc[32], sb2[32];
    int t = threadIdx.x;
    int img = blockIdx.z, c0 = blockIdx.y * 32, p0 = blockIdx.x * 64;
    if (t < 32) {
        int c = c0 + t;
        float mean = stats[2 * c] * invcnt;
        float var = fmaxf(stats[2 * c + 1] * invcnt - mean * mean, 0.f);
        smean[t] = mean;
        ssc[t] = gamma[c] / sqrtf(var + 1e-5f);
        sb2[t] = beta[c];
    }
    __syncthreads();
    const float* xi = x + (((size_t)img * C) << HWlog);
    u16* oi = out + ((size_t)img << HWlog) * C;
#pragma unroll
    for (int i = 0; i < 8; ++i) {
        int e = t + i * 256;
        int cl = e >> 6, pp = e & 63;
        float v = xi[(((size_t)(c0 + cl)) << HWlog) + p0 + pp];
        tile[cl * 65 + pp] = (v - smean[cl]) * ssc[cl] + sb2[cl];
    }
    __syncthreads();
#pragma unroll
    for (int i = 0; i < 8; ++i) {
        int e = t + i * 256;
        int cl = e & 31, pp = e >> 5;
        oi[(size_t)(p0 + pp) * C + c0 + cl] = f2bf(tile[cl * 65 + pp]);
    }
}

// ---------------------------------------------------------------------------
// Deform, NHWC bf16. off is fp32 [img-in-chunk][2C][HW] (GEMM output); for
// flat (c,p) pair idx_pc, (dy,dx) = float2 at off_img + 2*idx_pc. Phase 1
// stages offsets p-major (coalesced float2) into LDS; phase 2 is c-major:
// gathers channel-contiguous act, writes coalesced NHWC bf16.
// grid (HW/64, C/32, Nchunk); act/out pointers pre-offset to chunk start.
// ---------------------------------------------------------------------------
__global__ __launch_bounds__(256) void deform_nhwc_k(
    const u16* __restrict__ actb, const float* __restrict__ off,
    u16* __restrict__ out, int C, int HWlog, int Wlog, int H, int W)
{
    __shared__ float DY[32 * 65], DX[32 * 65];
    int t = threadIdx.x;
    int img = blockIdx.z, c0 = blockIdx.y * 32, p0 = blockIdx.x * 64;
    const float* offg = off + (size_t)img * (((size_t)2 * C) << HWlog);
#pragma unroll
    for (int i = 0; i < 8; ++i) {
        int e = t + i * 256;
        int cl = e >> 6, pp = e & 63;
        size_t idx_pc = (((size_t)(c0 + cl)) << HWlog) + p0 + pp;
        float2 o = *(const float2*)(offg + 2 * idx_pc);
        DY[cl * 65 + pp] = o.x;
        DX[cl * 65 + pp] = o.y;
    }
    __syncthreads();
    const u16* ai = actb + ((size_t)img << HWlog) * C;
    u16* oi = out + ((size_t)img << HWlog) * C;
#pragma unroll
    for (int i = 0; i < 8; ++i) {
        int e = t + i * 256;
        int cl = e & 31, pp = e >> 5;
        int c = c0 + cl, p = p0 + pp;
        int yy = p >> Wlog, xx = p & (W - 1);
        float cy = fminf(fmaxf((float)yy + DY[cl * 65 + pp], 0.f), (float)(H - 1));
        float cx = fminf(fmaxf((float)xx + DX[cl * 65 + pp], 0.f), (float)(W - 1));
        float y0f = floorf(cy), x0f = floorf(cx);
        float ty = cy - y0f, tx = cx - x0f;
        int y0 = (int)y0f, y1 = (int)ceilf(cy);
        int x0 = (int)x0f, x1 = (int)ceilf(cx);
        float vlt = bf2f(ai[(size_t)(y0 * W + x0) * C + c]);
        float vrt = bf2f(ai[(size_t)(y1 * W + x0) * C + c]);
        float vlb = bf2f(ai[(size_t)(y0 * W + x1) * C + c]);
        float vrb = bf2f(ai[(size_t)(y1 * W + x1) * C + c]);
        float vt = ty * (vrt - vlt) + vlt;
        float vb = ty * (vrb - vlb) + vlb;
        oi[(size_t)p * C + c] = f2bf(tx * (vb - vt) + vt);
    }
}

// ---------------------------------------------------------------------------
__global__ __launch_bounds__(64) void gap_k(
    const float* __restrict__ x, float* __restrict__ pooled, int HW, float inv)
{
    int bc = blockIdx.x;
    float s = 0.f;
    for (int i = threadIdx.x; i < HW; i += 64) s += x[(size_t)bc * HW + i];
#pragma unroll
    for (int d = 32; d > 0; d >>= 1) s += __shfl_down(s, d);
    if (threadIdx.x == 0) pooled[bc] = s * inv;
}

__global__ __launch_bounds__(64) void fc_softmax_k(
    const float* __restrict__ pooled, const float* __restrict__ fw,
    const float* __restrict__ fb, float* __restrict__ outp)
{
    int n = blockIdx.x;
    __shared__ float logits[10];
    int k = threadIdx.x;
    if (k < 10) {
        float s = fb[k];
        const float* row = pooled + n * 128;
        const float* wr  = fw + k * 128;
        for (int c = 0; c < 128; ++c) s += row[c] * wr[c];
        logits[k] = s;
    }
    __syncthreads();
    if (k < 10) {
        float m = logits[0];
#pragma unroll
        for (int j = 1; j < 10; ++j) m = fmaxf(m, logits[j]);
        float den = 0.f;
#pragma unroll
        for (int j = 0; j < 10; ++j) den += expf(logits[j] - m);
        outp[n * 10 + k] = expf(logits[k] - m) / den;
    }
}

// ---------------------------------------------------------------------------
// Workspace budget (proven safe in R2: ws_size >= ~149 MB):
//   SCRATCH 16,777,216 f (64 MB)  -- CONVOUT (fp32 NCHW) and OFF chunks share
//   ACTB0   16,777,216 u16 (32 MB)
//   ACTB1   16,777,216 u16 (32 MB)
//   WBF     626,688 u16 (~1.2 MB) + STATS/POOLED
// total ~135.5 MB. CONVOUT and OFF lifetimes are disjoint:
// convGEMM->CONVOUT -> bn_t -> ACTB0 (CONVOUT dead) -> offGEMM->OFF ->
// deform (OFF dead) -> next convGEMM->CONVOUT. Off stages 1/3 chunk 2x16
// images so the OFF chunk fits 64 MB; stage 2 fits whole.
// ---------------------------------------------------------------------------
extern "C" void kernel_launch(void* const* d_in, const int* in_sizes, int n_in,
                              void* d_out, int out_size, void* d_ws, size_t ws_size,
                              hipStream_t stream)
{
    const float* x     = (const float*)d_in[0];
    const float* c11w  = (const float*)d_in[1];
    const float* c11b  = (const float*)d_in[2];
    const float* bn11g = (const float*)d_in[3];
    const float* bn11b = (const float*)d_in[4];
    const float* o12w  = (const float*)d_in[5];
    const float* c12w  = (const float*)d_in[6];
    const float* c12b  = (const float*)d_in[7];
    const float* bn12g = (const float*)d_in[8];
    const float* bn12b = (const float*)d_in[9];
    const float* o21w  = (const float*)d_in[10];
    const float* c21w  = (const float*)d_in[11];
    const float* c21b  = (const float*)d_in[12];
    const float* bn21g = (const float*)d_in[13];
    const float* bn21b = (const float*)d_in[14];
    const float* o22w  = (const float*)d_in[15];
    const float* c22w  = (const float*)d_in[16];
    const float* c22b  = (const float*)d_in[17];
    const float* bn22g = (const float*)d_in[18];
    const float* bn22b = (const float*)d_in[19];
    const float* fcw   = (const float*)d_in[20];
    const float* fcb   = (const float*)d_in[21];
    float* outp = (float*)d_out;

    const int N = 32;
    float* ws      = (float*)d_ws;
    float* SCRATCH = ws;                          // 16,777,216 floats (64 MB)
    u16*   ACTB0   = (u16*)(ws + 16777216);       // 16,777,216 u16 (32 MB)
    u16*   ACTB1   = (u16*)(ws + 25165824);       // 16,777,216 u16 (32 MB)
    u16*   WBF     = (u16*)(ws + 33554432);       // 626,688 u16
    float* STATS   = ws + 33867776;               // 256
    float* POOLED  = STATS + 256;                 // 4096  (ends ~33,872,128 f)

    u16* wo12 = WBF + 0;
    u16* wc12 = WBF + 18432;
    u16* wo21 = WBF + 36864;
    u16* wc21 = WBF + 110592;
    u16* wo22 = WBF + 184320;
    u16* wc22 = WBF + 479232;
    auto cast = [&](const float* s, u16* d, int Cout, int Cin) {
        int n = Cout * Cin * 9;
        cast_perm_k<<<(n + TPB - 1) / TPB, TPB, 0, stream>>>(s, d, Cout, Cin);
    };
    cast(o12w, wo12, 64, 32);
    cast(c12w, wc12, 64, 32);
    cast(o21w, wo21, 128, 64);
    cast(c21w, wc21, 128, 64);
    cast(o22w, wo22, 256, 128);
    cast(c22w, wc22, 128, 128);

    auto gemm = [&](const u16* A, const u16* actb, float* Cp, const float* bias,
                    int M, int K, int Npix, int relu, int Cin, int CPWlog,
                    int H, int W, int Wolog, int stride, int nimg) {
        if (M == 64) {
            dim3 g(Npix / 256, 1, nimg);
            gemm_impl_k<1, 4><<<g, TPB, 0, stream>>>(A, actb, Cp, bias, M, K,
                Npix, relu, Cin, CPWlog, H, W, Wolog, stride);
        } else {
            dim3 g(Npix / 128, M / 128, nimg);
            gemm_impl_k<2, 2><<<g, TPB, 0, stream>>>(A, actb, Cp, bias, M, K,
                Npix, relu, Cin, CPWlog, H, W, Wolog, stride);
        }
    };
    auto bn_t = [&](const float* src, const float* g_, const float* b_,
                    u16* dst, int C, int HWlog) {
        int HW = 1 << HWlog, NHW = N * HW;
        zero_k<<<1, TPB, 0, stream>>>(STATS, 256);
        dim3 gs(32, C);
        bn_stats_k<<<gs, TPB, 0, stream>>>(src, STATS, C, HWlog, NHW, 32);
        dim3 ga(HW / 64, C / 32, N);
        bn_apply_t_k<<<ga, TPB, 0, stream>>>(src, STATS, g_, b_, dst, C, HWlog,
                                             1.f / (float)NHW);
    };
    // chunked offset-conv + deform: per chunk of `nc` images, off-GEMM into
    // SCRATCH then bilinear gather ACTB0->ACTB1
    auto deform_stage = [&](const u16* woff, int C, int HWlog, int Wlog,
                            int H, int W, int K, int CPWlog, int nc) {
        int HW = 1 << HWlog;
        for (int g0 = 0; g0 < N; g0 += nc) {
            const u16* src = ACTB0 + (size_t)g0 * HW * C;
            gemm(woff, src, SCRATCH, nullptr, 2 * C, K, HW, 0, C, CPWlog,
                 H, W, Wlog, 1, nc);
            dim3 g(HW / 64, C / 32, nc);
            deform_nhwc_k<<<g, TPB, 0, stream>>>(
                src, SCRATCH, ACTB1 + (size_t)g0 * HW * C, C, HWlog, Wlog, H, W);
        }
    };

    // ---- conv11 (1->32, 128x128, s1, direct) + relu -> fp32 NCHW ----
    {
        dim3 g(8, 8, N * 8);
        conv3x3_k<1><<<g, TPB, 0, stream>>>(x, c11w, c11b, SCRATCH, N, 1, 128,
                                            128, 32, 128, 128, 1, 0);
    }
    bn_t(SCRATCH, bn11g, bn11b, ACTB0, 32, 14);   // -> NHWC bf16 [16384][32]

    // ---- deform12 (C=32 @128x128): OFF chunk 16 img * 64ch * 16384 = 16M f ----
    deform_stage(wo12, 32, 14, 7, 128, 128, 288, 0, 16);
    // ---- conv12 (32->64, s2) ----
    gemm(wc12, ACTB1, SCRATCH, c12b, 64, 288, 4096, 1, 32, 0, 128, 128, 6, 2, N);
    bn_t(SCRATCH, bn12g, bn12b, ACTB0, 64, 12);   // -> [4096][64]

    // ---- deform21 (C=64 @64x64): 32 img * 128ch * 4096 = 16M f, one pass ----
    deform_stage(wo21, 64, 12, 6, 64, 64, 576, 1, 32);
    // ---- conv21 (64->128, s1) ----
    gemm(wc21, ACTB1, SCRATCH, c21b, 128, 576, 4096, 1, 64, 1, 64, 64, 6, 1, N);
    bn_t(SCRATCH, bn21g, bn21b, ACTB0, 128, 12);  // -> [4096][128]

    // ---- deform22 (C=128 @64x64): chunk 16 img * 256ch * 4096 = 16M f ----
    deform_stage(wo22, 128, 12, 6, 64, 64, 1152, 2, 16);
    // ---- conv22 (128->128, s2) ----
    gemm(wc22, ACTB1, SCRATCH, c22b, 128, 1152, 1024, 1, 128, 2, 64, 64, 5, 2, N);
    {   // bn22 in place (fp32 NCHW), GAP follows
        int HW = 1024, NHW = N * HW, total = N * 128 * HW;
        zero_k<<<1, TPB, 0, stream>>>(STATS, 256);
        dim3 gs(32, 128);
        bn_stats_k<<<gs, TPB, 0, stream>>>(SCRATCH, STATS, 128, 10, NHW, 32);
        bn_apply_k<<<(total + TPB - 1) / TPB, TPB, 0, stream>>>(
            SCRATCH, STATS, bn22g, bn22b, 127, 10, 1.f / (float)NHW, total);
    }

    // ---- GAP + FC + softmax ----
    gap_k<<<N * 128, 64, 0, stream>>>(SCRATCH, POOLED, 1024, 1.f / 1024.f);
    fc_softmax_k<<<N, 64, 0, stream>>>(POOLED, fcw, fcb, outp);
}

// Round 5
// 798.397 us; speedup vs baseline: 7.9800x; 1.1369x over previous
//
#include <hip/hip_runtime.h>
#include <math.h>

#define TPB 256
typedef unsigned short u16;
typedef short v8s __attribute__((ext_vector_type(8)));
typedef float v4f __attribute__((ext_vector_type(4)));

__device__ __forceinline__ u16 f2bf(float v) {
    unsigned int u = __builtin_bit_cast(unsigned int, v);
    return (u16)((u + 0x7fffu + ((u >> 16) & 1u)) >> 16);
}
__device__ __forceinline__ float bf2f(u16 v) {
    return __builtin_bit_cast(float, (unsigned int)v << 16);
}

typedef const __attribute__((address_space(1))) unsigned int* gp1_t;
typedef __attribute__((address_space(3))) unsigned int* lp3_t;
__device__ __forceinline__ void gload_lds16(const void* g, void* l) {
    __builtin_amdgcn_global_load_lds((gp1_t)g, (lp3_t)l, 16, 0, 0);
}

// ---------------------------------------------------------------------------
// weight cast + permute: OIHW fp32 -> [co][ky*3+kx][ci] bf16
// ---------------------------------------------------------------------------
__global__ __launch_bounds__(256) void cast_perm_k(
    const float* __restrict__ src, u16* __restrict__ dst, int Cout, int Cin)
{
    int i = blockIdx.x * TPB + threadIdx.x;
    int total = Cout * Cin * 9;
    if (i >= total) return;
    int ci = i % Cin, rest = i / Cin;
    int w = rest % 9, co = rest / 9;
    dst[i] = f2bf(src[(co * Cin + ci) * 9 + w]);
}

__global__ __launch_bounds__(256) void zero4_k(uint4* __restrict__ p, int n)
{
    int i = blockIdx.x * TPB + threadIdx.x;
    if (i < n) p[i] = (uint4){0u, 0u, 0u, 0u};
}

// ---------------------------------------------------------------------------
// Implicit-GEMM conv from HALO'ed NHWC bf16 act ((H+2)x(W+2)xC per image,
// interior pixel (y,x) at ((y+1)*Wpad+(x+1))*C). Halo = zeros -> no boundary
// predication -> every B row-chunk is an unconditional 16B global_load_lds.
// K-loop: double-buffered LDS; loads for step k+1 issued right after the
// barrier and drained by the NEXT iteration's vmcnt(0) -> fetch overlaps MFMA.
// LDS layout: per row 4 chunks of 16B at position c ^ ((row>>1)&3) (XOR
// swizzle): DMA dest stays lane-contiguous AND ds_read_b128 frag reads are
// 2-way bank-aliased only (free). Block = 4 waves, wave tile 64x64
// (4x4 mfma 16x16x32); block tile (WGM*64)x(WGN*64).
// ---------------------------------------------------------------------------
template <int WGM, int WGN>
__global__ __launch_bounds__(256) void gemm_impl_k(
    const u16* __restrict__ A, const u16* __restrict__ act, float* __restrict__ C,
    const float* __restrict__ bias, int M, int K, int Npix, int relu,
    int Cin, int CPWlog, int Wpad, int Wolog, int stride, size_t astride)
{
    constexpr int BM = WGM * 64, BN = WGN * 64;
    constexpr int ASLOTS = BM / 16, BSLOTS = BN / 16;
    constexpr int SLOTS = ASLOTS + BSLOTS, SPW = SLOTS / 4;
    __shared__ u16 lds[2][(BM + BN) * 32];
    const int t = threadIdx.x, lane = t & 63, wave = t >> 6;
    const int g = blockIdx.z;
    const int p0 = blockIdx.x * BN, m0 = blockIdx.y * BM;
    const u16* actg = act + (size_t)g * astride;
    const int Wo = 1 << Wolog;

    // per-lane source base for each owned DMA slot (A slots then B slots)
    const u16* src[SPW];
#pragma unroll
    for (int i = 0; i < SPW; ++i) {
        int s = wave * SPW + i;
        if (s < ASLOTS) {
            int ch = s * 64 + lane, nr = ch >> 2, cst = ch & 3;
            int csrc = cst ^ ((nr >> 1) & 3);
            src[i] = A + (size_t)(m0 + nr) * K + csrc * 8;
        } else {
            int ch = (s - ASLOTS) * 64 + lane, nr = ch >> 2, cst = ch & 3;
            int csrc = cst ^ ((nr >> 1) & 3);
            int p = p0 + nr, oy = p >> Wolog, ox = p & (Wo - 1);
            src[i] = actg + (size_t)(oy * stride * Wpad + ox * stride) * Cin + csrc * 8;
        }
    }

    auto issue = [&](int kk, int buf) {
        int k0 = kk << 5;
        int w = kk >> CPWlog;
        int ci0 = (kk & ((1 << CPWlog) - 1)) << 5;
        int koff = (w / 3 * Wpad + w % 3) * Cin + ci0;
#pragma unroll
        for (int i = 0; i < SPW; ++i) {
            int s = wave * SPW + i;
            const u16* sp = src[i] + ((s < ASLOTS) ? k0 : koff);
            gload_lds16(sp, lds[buf] + s * 512);
        }
    };

    v4f acc[4][4];
#pragma unroll
    for (int mi = 0; mi < 4; ++mi)
#pragma unroll
        for (int ni = 0; ni < 4; ++ni) acc[mi][ni] = (v4f){0.f, 0.f, 0.f, 0.f};

    const int wm = wave % WGM, wn = wave / WGM;
    const int la = lane & 15, quad = lane >> 4;

    issue(0, 0);
    const int nk = K >> 5;
    for (int kk = 0; kk < nk; ++kk) {
        int buf = kk & 1;
        asm volatile("s_waitcnt vmcnt(0)\n\ts_barrier" ::: "memory");
        if (kk + 1 < nk) issue(kk + 1, buf ^ 1);
        const u16* Lb = lds[buf];
        v8s a[4], b[4];
#pragma unroll
        for (int mi = 0; mi < 4; ++mi) {
            int r = wm * 64 + mi * 16 + la;
            a[mi] = *(const v8s*)(Lb + (r * 4 + (quad ^ ((r >> 1) & 3))) * 8);
        }
#pragma unroll
        for (int ni = 0; ni < 4; ++ni) {
            int r = wn * 64 + ni * 16 + la;
            b[ni] = *(const v8s*)(Lb + BM * 32 + (r * 4 + (quad ^ ((r >> 1) & 3))) * 8);
        }
#pragma unroll
        for (int mi = 0; mi < 4; ++mi)
#pragma unroll
            for (int ni = 0; ni < 4; ++ni)
                acc[mi][ni] = __builtin_amdgcn_mfma_f32_16x16x32_bf16(
                    a[mi], b[ni], acc[mi][ni], 0, 0, 0);
    }

    float* Cimg = C + (size_t)g * M * Npix;
#pragma unroll
    for (int mi = 0; mi < 4; ++mi) {
#pragma unroll
        for (int r = 0; r < 4; ++r) {
            int row = m0 + wm * 64 + mi * 16 + quad * 4 + r;
            float bv = bias ? bias[row] : 0.f;
#pragma unroll
            for (int ni = 0; ni < 4; ++ni) {
                int col = p0 + wn * 64 + ni * 16 + la;
                float v = acc[mi][ni][r] + bv;
                if (relu) v = fmaxf(v, 0.f);
                Cimg[(size_t)row * Npix + col] = v;
            }
        }
    }
}

// ---------------------------------------------------------------------------
// Direct 3x3 conv (conv11 only, Cin=1), fp32 NCHW out
// ---------------------------------------------------------------------------
template <int STRIDE>
__global__ __launch_bounds__(256) void conv3x3_k(
    const float* __restrict__ in, const float* __restrict__ wgt,
    const float* __restrict__ bias, float* __restrict__ out,
    int N, int Cin, int H, int W, int Cout_buf, int Ho, int Wo,
    int relu, int co_base)
{
    constexpr int IT = 15 * STRIDE + 3;
    __shared__ float tile[IT * IT];
    const int tid = threadIdx.x;
    const int tx = tid & 15, ty = tid >> 4;
    const int coutg = Cout_buf >> 2;
    const int n = blockIdx.z / coutg;
    const int cog = blockIdx.z - n * coutg;
    const int co0 = cog << 2;
    const int ox = (blockIdx.x << 4) + tx;
    const int oy = (blockIdx.y << 4) + ty;
    const int ix0 = (blockIdx.x << 4) * STRIDE - 1;
    const int iy0 = (blockIdx.y << 4) * STRIDE - 1;
    const float* inN = in + (size_t)n * Cin * H * W;
    float acc[4] = {0.f, 0.f, 0.f, 0.f};

    for (int ci = 0; ci < Cin; ++ci) {
        const float* plane = inN + (size_t)ci * H * W;
        __syncthreads();
        for (int i = tid; i < IT * IT; i += TPB) {
            int r = i / IT, c = i - r * IT;
            int yy = iy0 + r, xx = ix0 + c;
            float v = 0.f;
            if (yy >= 0 && yy < H && xx >= 0 && xx < W) v = plane[yy * W + xx];
            tile[i] = v;
        }
        __syncthreads();
        const int ly = ty * STRIDE, lx = tx * STRIDE;
        float nb[9];
#pragma unroll
        for (int ky = 0; ky < 3; ++ky)
#pragma unroll
            for (int kx = 0; kx < 3; ++kx)
                nb[ky * 3 + kx] = tile[(ly + ky) * IT + lx + kx];
        const float* wp = wgt + ((size_t)(co_base + co0) * Cin + ci) * 9;
#pragma unroll
        for (int j = 0; j < 4; ++j) {
            const float* w9 = wp + (size_t)j * Cin * 9;
            float a = acc[j];
#pragma unroll
            for (int k = 0; k < 9; ++k) a += nb[k] * w9[k];
            acc[j] = a;
        }
    }
#pragma unroll
    for (int j = 0; j < 4; ++j) {
        float v = acc[j];
        if (bias) v += bias[co_base + co0 + j];
        if (relu) v = fmaxf(v, 0.f);
        out[(((size_t)n * Cout_buf + (co0 + j)) * Ho + oy) * Wo + ox] = v;
    }
}

// ---------------------------------------------------------------------------
// BatchNorm
// ---------------------------------------------------------------------------
__global__ void zero_k(float* p, int n)
{
    int i = blockIdx.x * TPB + threadIdx.x;
    if (i < n) p[i] = 0.f;
}

__global__ __launch_bounds__(256) void bn_stats_k(
    const float* __restrict__ x, float* __restrict__ stats,
    int C, int HWlog, int NHW, int SPLIT)
{
    const int c = blockIdx.y, sb = blockIdx.x, tid = threadIdx.x;
    const int HWm = (1 << HWlog) - 1;
    float s = 0.f, s2 = 0.f;
    for (int i = sb * TPB + tid; i < NHW; i += SPLIT * TPB) {
        int nn = i >> HWlog, p = i & HWm;
        float v = x[(((size_t)nn * C + c) << HWlog) + p];
        s += v;
        s2 += v * v;
    }
    __shared__ float r1[TPB], r2[TPB];
    r1[tid] = s; r2[tid] = s2;
    __syncthreads();
    for (int d = TPB / 2; d > 0; d >>= 1) {
        if (tid < d) { r1[tid] += r1[tid + d]; r2[tid] += r2[tid + d]; }
        __syncthreads();
    }
    if (tid == 0) {
        atomicAdd(&stats[2 * c], r1[0]);
        atomicAdd(&stats[2 * c + 1], r2[0]);
    }
}

// in-place fp32 NCHW apply (last BN only)
__global__ __launch_bounds__(256) void bn_apply_k(
    float* __restrict__ x, const float* __restrict__ stats,
    const float* __restrict__ g, const float* __restrict__ b,
    int Cm1, int HWlog, float invcnt, int total)
{
    int idx = blockIdx.x * TPB + threadIdx.x;
    if (idx >= total) return;
    int c = (idx >> HWlog) & Cm1;
    float mean = stats[2 * c] * invcnt;
    float var  = fmaxf(stats[2 * c + 1] * invcnt - mean * mean, 0.f);
    float sc   = g[c] / sqrtf(var + 1e-5f);
    x[idx] = (x[idx] - mean) * sc + b[c];
}

// fused BN-apply + NCHW->halo'ed-NHWC transpose + bf16 cast.
// grid (HW/64, C/32, N)
__global__ __launch_bounds__(256) void bn_apply_t_k(
    const float* __restrict__ x, const float* __restrict__ stats,
    const float* __restrict__ gamma, const float* __restrict__ beta,
    u16* __restrict__ out, int C, int HWlog, int Wlog, int Wpad,
    size_t ostride, float invcnt)
{
    __shared__ float tile[32 * 65];
    __shared__ float smean[32], ssc[32], sb2[32];
    int t = threadIdx.x;
    int img = blockIdx.z, c0 = blockIdx.y * 32, p0 = blockIdx.x * 64;
    if (t < 32) {
        int c = c0 + t;
        float mean = stats[2 * c] * invcnt;
        float var = fmaxf(stats[2 * c + 1] * invcnt - mean * mean, 0.f);
        smean[t] = mean;
        ssc[t] = gamma[c] / sqrtf(var + 1e-5f);
        sb2[t] = beta[c];
    }
    __syncthreads();
    const float* xi = x + (((size_t)img * C) << HWlog);
    u16* oi = out + (size_t)img * ostride;
    const int Wm1 = (1 << Wlog) - 1;
#pragma unroll
    for (int i = 0; i < 8; ++i) {
        int e = t + i * 256;
        int cl = e >> 6, pp = e & 63;
        float v = xi[(((size_t)(c0 + cl)) << HWlog) + p0 + pp];
        tile[cl * 65 + pp] = (v - smean[cl]) * ssc[cl] + sb2[cl];
    }
    __syncthreads();
#pragma unroll
    for (int i = 0; i < 8; ++i) {
        int e = t + i * 256;
        int cl = e & 31, pp = e >> 5;
        int p = p0 + pp, y = p >> Wlog, xx = p & Wm1;
        oi[((size_t)(y + 1) * Wpad + (xx + 1)) * C + c0 + cl] =
            f2bf(tile[cl * 65 + pp]);
    }
}

// ---------------------------------------------------------------------------
// Deform on halo'ed NHWC bf16. off is fp32 [img-in-chunk][2C][HW]; for flat
// (c,p): (dy,dx) = float2 at off_img + 2*(c*HW+p). Phase 1 stages offsets
// p-major into LDS; phase 2 c-major gather + coalesced halo'ed NHWC write.
// ---------------------------------------------------------------------------
__global__ __launch_bounds__(256) void deform_nhwc_k(
    const u16* __restrict__ actb, const float* __restrict__ off,
    u16* __restrict__ out, int C, int HWlog, int Wlog, int H, int W,
    int Wpad, size_t astride)
{
    __shared__ float DY[32 * 65], DX[32 * 65];
    int t = threadIdx.x;
    int img = blockIdx.z, c0 = blockIdx.y * 32, p0 = blockIdx.x * 64;
    const float* offg = off + (size_t)img * (((size_t)2 * C) << HWlog);
#pragma unroll
    for (int i = 0; i < 8; ++i) {
        int e = t + i * 256;
        int cl = e >> 6, pp = e & 63;
        size_t idx_pc = (((size_t)(c0 + cl)) << HWlog) + p0 + pp;
        float2 o = *(const float2*)(offg + 2 * idx_pc);
        DY[cl * 65 + pp] = o.x;
        DX[cl * 65 + pp] = o.y;
    }
    __syncthreads();
    const u16* ai = actb + (size_t)img * astride;
    u16* oi = out + (size_t)img * astride;
#pragma unroll
    for (int i = 0; i < 8; ++i) {
        int e = t + i * 256;
        int cl = e & 31, pp = e >> 5;
        int c = c0 + cl, p = p0 + pp;
        int yy = p >> Wlog, xx = p & (W - 1);
        float cy = fminf(fmaxf((float)yy + DY[cl * 65 + pp], 0.f), (float)(H - 1));
        float cx = fminf(fmaxf((float)xx + DX[cl * 65 + pp], 0.f), (float)(W - 1));
        float y0f = floorf(cy), x0f = floorf(cx);
        float ty = cy - y0f, tx = cx - x0f;
        int y0 = (int)y0f, y1 = (int)ceilf(cy);
        int x0 = (int)x0f, x1 = (int)ceilf(cx);
        float vlt = bf2f(ai[((size_t)(y0 + 1) * Wpad + (x0 + 1)) * C + c]);
        float vrt = bf2f(ai[((size_t)(y1 + 1) * Wpad + (x0 + 1)) * C + c]);
        float vlb = bf2f(ai[((size_t)(y0 + 1) * Wpad + (x1 + 1)) * C + c]);
        float vrb = bf2f(ai[((size_t)(y1 + 1) * Wpad + (x1 + 1)) * C + c]);
        float vt = ty * (vrt - vlt) + vlt;
        float vb = ty * (vrb - vlb) + vlb;
        oi[((size_t)(yy + 1) * Wpad + (xx + 1)) * C + c] = f2bf(tx * (vb - vt) + vt);
    }
}

// ---------------------------------------------------------------------------
__global__ __launch_bounds__(64) void gap_k(
    const float* __restrict__ x, float* __restrict__ pooled, int HW, float inv)
{
    int bc = blockIdx.x;
    float s = 0.f;
    for (int i = threadIdx.x; i < HW; i += 64) s += x[(size_t)bc * HW + i];
#pragma unroll
    for (int d = 32; d > 0; d >>= 1) s += __shfl_down(s, d);
    if (threadIdx.x == 0) pooled[bc] = s * inv;
}

__global__ __launch_bounds__(64) void fc_softmax_k(
    const float* __restrict__ pooled, const float* __restrict__ fw,
    const float* __restrict__ fb, float* __restrict__ outp)
{
    int n = blockIdx.x;
    __shared__ float logits[10];
    int k = threadIdx.x;
    if (k < 10) {
        float s = fb[k];
        const float* row = pooled + n * 128;
        const float* wr  = fw + k * 128;
        for (int c = 0; c < 128; ++c) s += row[c] * wr[c];
        logits[k] = s;
    }
    __syncthreads();
    if (k < 10) {
        float m = logits[0];
#pragma unroll
        for (int j = 1; j < 10; ++j) m = fmaxf(m, logits[j]);
        float den = 0.f;
#pragma unroll
        for (int j = 0; j < 10; ++j) den += expf(logits[j] - m);
        outp[n * 10 + k] = expf(logits[k] - m) / den;
    }
}

// ---------------------------------------------------------------------------
// Workspace (proven safe: ws_size >= ~149 MB from R2; used here ~143.9 MB):
//   SCRATCH 16,777,216 f (64 MB)  -- fp32 conv out / offset chunks (disjoint)
//   ACTB0   18,874,368 u16 (36 MB, halo'ed NHWC)
//   ACTB1   18,874,368 u16 (36 MB)
//   WBF     626,688 u16 + STATS/POOLED
// Halo'ed sizes: 130*130*32=540,800 u16/img (st1), 66*66*64=278,784 (st2),
// 66*66*128=557,568 (st3); x32 img <= 17,842,176 u16 < 18,874,368. ACTB0/1
// fully zeroed each launch (ws re-poisoned 0xAA) so halos are zero.
// ---------------------------------------------------------------------------
extern "C" void kernel_launch(void* const* d_in, const int* in_sizes, int n_in,
                              void* d_out, int out_size, void* d_ws, size_t ws_size,
                              hipStream_t stream)
{
    const float* x     = (const float*)d_in[0];
    const float* c11w  = (const float*)d_in[1];
    const float* c11b  = (const float*)d_in[2];
    const float* bn11g = (const float*)d_in[3];
    const float* bn11b = (const float*)d_in[4];
    const float* o12w  = (const float*)d_in[5];
    const float* c12w  = (const float*)d_in[6];
    const float* c12b  = (const float*)d_in[7];
    const float* bn12g = (const float*)d_in[8];
    const float* bn12b = (const float*)d_in[9];
    const float* o21w  = (const float*)d_in[10];
    const float* c21w  = (const float*)d_in[11];
    const float* c21b  = (const float*)d_in[12];
    const float* bn21g = (const float*)d_in[13];
    const float* bn21b = (const float*)d_in[14];
    const float* o22w  = (const float*)d_in[15];
    const float* c22w  = (const float*)d_in[16];
    const float* c22b  = (const float*)d_in[17];
    const float* bn22g = (const float*)d_in[18];
    const float* bn22b = (const float*)d_in[19];
    const float* fcw   = (const float*)d_in[20];
    const float* fcb   = (const float*)d_in[21];
    float* outp = (float*)d_out;

    const int N = 32;
    float* ws      = (float*)d_ws;
    float* SCRATCH = ws;                          // 16,777,216 floats (64 MB)
    u16*   ACTB0   = (u16*)(ws + 16777216);       // 18,874,368 u16 (36 MB)
    u16*   ACTB1   = (u16*)(ws + 26214400);       // 18,874,368 u16 (36 MB)
    u16*   WBF     = (u16*)(ws + 35651584);       // 626,688 u16
    float* STATS   = ws + 35964928;               // 256
    float* POOLED  = STATS + 256;                 // 4096 (end ~35,969,280 f)

    // zero both act buffers (halos must be 0; ws is poisoned every call)
    zero4_k<<<(4718592 + TPB - 1) / TPB, TPB, 0, stream>>>(
        (uint4*)ACTB0, 4718592);                  // 2 x 18,874,368 u16 = 72 MB

    u16* wo12 = WBF + 0;
    u16* wc12 = WBF + 18432;
    u16* wo21 = WBF + 36864;
    u16* wc21 = WBF + 110592;
    u16* wo22 = WBF + 184320;
    u16* wc22 = WBF + 479232;
    auto cast = [&](const float* s, u16* d, int Cout, int Cin) {
        int n = Cout * Cin * 9;
        cast_perm_k<<<(n + TPB - 1) / TPB, TPB, 0, stream>>>(s, d, Cout, Cin);
    };
    cast(o12w, wo12, 64, 32);
    cast(c12w, wc12, 64, 32);
    cast(o21w, wo21, 128, 64);
    cast(c21w, wc21, 128, 64);
    cast(o22w, wo22, 256, 128);
    cast(c22w, wc22, 128, 128);

    auto gemm = [&](const u16* A, const u16* actb, float* Cp, const float* bias,
                    int M, int K, int Npix, int relu, int Cin, int CPWlog,
                    int Wpad, int Wolog, int stride, size_t astride, int nimg) {
        if (M == 64) {
            dim3 g(Npix / 256, 1, nimg);
            gemm_impl_k<1, 4><<<g, TPB, 0, stream>>>(A, actb, Cp, bias, M, K,
                Npix, relu, Cin, CPWlog, Wpad, Wolog, stride, astride);
        } else {
            dim3 g(Npix / 128, M / 128, nimg);
            gemm_impl_k<2, 2><<<g, TPB, 0, stream>>>(A, actb, Cp, bias, M, K,
                Npix, relu, Cin, CPWlog, Wpad, Wolog, stride, astride);
        }
    };
    auto bn_t = [&](const float* src, const float* g_, const float* b_,
                    u16* dst, int C, int HWlog, int Wlog, int Wpad,
                    size_t ostride) {
        int HW = 1 << HWlog, NHW = N * HW;
        zero_k<<<1, TPB, 0, stream>>>(STATS, 256);
        dim3 gs(32, C);
        bn_stats_k<<<gs, TPB, 0, stream>>>(src, STATS, C, HWlog, NHW, 32);
        dim3 ga(HW / 64, C / 32, N);
        bn_apply_t_k<<<ga, TPB, 0, stream>>>(src, STATS, g_, b_, dst, C, HWlog,
                                             Wlog, Wpad, ostride,
                                             1.f / (float)NHW);
    };
    // chunked offset-conv + deform (off-GEMM chunk output fits SCRATCH 64 MB)
    auto deform_stage = [&](const u16* woff, int C, int HWlog, int Wlog,
                            int H, int W, int Wpad, size_t astride,
                            int K, int CPWlog, int nc) {
        int HW = 1 << HWlog;
        for (int g0 = 0; g0 < N; g0 += nc) {
            const u16* srcp = ACTB0 + (size_t)g0 * astride;
            gemm(woff, srcp, SCRATCH, nullptr, 2 * C, K, HW, 0, C, CPWlog,
                 Wpad, Wlog, 1, astride, nc);
            dim3 g(HW / 64, C / 32, nc);
            deform_nhwc_k<<<g, TPB, 0, stream>>>(
                srcp, SCRATCH, ACTB1 + (size_t)g0 * astride, C, HWlog, Wlog,
                H, W, Wpad, astride);
        }
    };

    const size_t AS1 = 540800;   // 130*130*32
    const size_t AS2 = 278784;   // 66*66*64
    const size_t AS3 = 557568;   // 66*66*128

    // ---- conv11 (1->32, 128x128, s1, direct) + relu -> fp32 NCHW ----
    {
        dim3 g(8, 8, N * 8);
        conv3x3_k<1><<<g, TPB, 0, stream>>>(x, c11w, c11b, SCRATCH, N, 1, 128,
                                            128, 32, 128, 128, 1, 0);
    }
    bn_t(SCRATCH, bn11g, bn11b, ACTB0, 32, 14, 7, 130, AS1);

    // ---- deform12 (C=32 @128x128): chunk 16 img (64ch*16384*16*4B = 64 MB) --
    deform_stage(wo12, 32, 14, 7, 128, 128, 130, AS1, 288, 0, 16);
    // ---- conv12 (32->64, s2) ----
    gemm(wc12, ACTB1, SCRATCH, c12b, 64, 288, 4096, 1, 32, 0, 130, 6, 2, AS1, N);
    bn_t(SCRATCH, bn12g, bn12b, ACTB0, 64, 12, 6, 66, AS2);

    // ---- deform21 (C=64 @64x64): one pass (128ch*4096*32*4B = 64 MB) ----
    deform_stage(wo21, 64, 12, 6, 64, 64, 66, AS2, 576, 1, 32);
    // ---- conv21 (64->128, s1) ----
    gemm(wc21, ACTB1, SCRATCH, c21b, 128, 576, 4096, 1, 64, 1, 66, 6, 1, AS2, N);
    bn_t(SCRATCH, bn21g, bn21b, ACTB0, 128, 12, 6, 66, AS3);

    // ---- deform22 (C=128 @64x64): chunk 16 img (256ch*4096*16*4B = 64 MB) --
    deform_stage(wo22, 128, 12, 6, 64, 64, 66, AS3, 1152, 2, 16);
    // ---- conv22 (128->128, s2) ----
    gemm(wc22, ACTB1, SCRATCH, c22b, 128, 1152, 1024, 1, 128, 2, 66, 5, 2, AS3, N);
    {   // bn22 in place (fp32 NCHW), GAP follows
        int HW = 1024, NHW = N * HW, total = N * 128 * HW;
        zero_k<<<1, TPB, 0, stream>>>(STATS, 256);
        dim3 gs(32, 128);
        bn_stats_k<<<gs, TPB, 0, stream>>>(SCRATCH, STATS, 128, 10, NHW, 32);
        bn_apply_k<<<(total + TPB - 1) / TPB, TPB, 0, stream>>>(
            SCRATCH, STATS, bn22g, bn22b, 127, 10, 1.f / (float)NHW, total);
    }

    // ---- GAP + FC + softmax ----
    gap_k<<<N * 128, 64, 0, stream>>>(SCRATCH, POOLED, 1024, 1.f / 1024.f);
    fc_softmax_k<<<N, 64, 0, stream>>>(POOLED, fcw, fcb, outp);
}